// Round 3
// baseline (1186.059 us; speedup 1.0000x reference)
//
#include <hip/hip_runtime.h>
#include <hip/hip_bf16.h>
#include <cstdint>
#include <cstddef>

#define B_    64
#define N_    2048
#define E_    32768            // edges per graph
#define DIM_  64
#define K1_   1639
#define K2_   1312
#define NTOT  (B_ * N_)        // 131072
#define ETOT  (B_ * E_)        // 2097152
#define N2TOT (B_ * K1_)       // 104896
#define NCLS  6

// ---------------- zero an int array ----------------
__global__ void k_zero(int* a, int n) {
    int i = blockIdx.x * 256 + threadIdx.x;
    if (i < n) a[i] = 0;
}

// ---------------- in-degree count (int atomics only) ----------------
template<bool REMAP>
__global__ void k_count(const int* src, const int* dst, const int* remap, int* deg) {
    int e = blockIdx.x * 256 + threadIdx.x;   // grid is exactly ETOT/256
    int d = dst[e];
    if (REMAP) {
        int s = remap[src[e]];
        d = remap[d];
        if ((s | d) < 0) return;              // edge touches a dropped node
    }
    atomicAdd(&deg[d], 1);
}

// ---------------- per-graph exclusive scan of deg -> CSR offsets ----------------
// one block per graph; zeroes fill cursor; precomputes rsqrt(deg+1)
template<int NLOC>
__launch_bounds__(256)
__global__ void k_scan(const int* deg, int* offs, int* cur, float* rsq) {
    __shared__ int ts[256];
    const int PER = (NLOC + 255) / 256;
    int g = blockIdx.x, tid = threadIdx.x;
    int c[PER];
    int s = 0;
#pragma unroll
    for (int i = 0; i < PER; i++) {
        int idx = tid * PER + i;
        c[i] = (idx < NLOC) ? deg[g * NLOC + idx] : 0;
        s += c[i];
    }
    ts[tid] = s;
    __syncthreads();
    for (int o = 1; o < 256; o <<= 1) {
        int v = (tid >= o) ? ts[tid - o] : 0;
        __syncthreads();
        ts[tid] += v;
        __syncthreads();
    }
    int run = ts[tid] - s + g * E_;           // global edge-slot base for this thread
#pragma unroll
    for (int i = 0; i < PER; i++) {
        int idx = tid * PER + i;
        if (idx < NLOC) {
            int node = g * NLOC + idx;
            offs[node] = run;
            cur[node] = 0;
            rsq[node] = rsqrtf((float)(c[i] + 1));
            run += c[i];
        }
    }
}

// ---------------- CSR fill: csr[offs[d] + slot] = s ----------------
template<bool REMAP>
__global__ void k_fill(const int* src, const int* dst, const int* remap,
                       const int* offs, int* cur, int* csr) {
    int e = blockIdx.x * 256 + threadIdx.x;   // grid is exactly ETOT/256
    int s = src[e], d = dst[e];
    if (REMAP) {
        s = remap[s]; d = remap[d];
        if ((s | d) < 0) return;
    }
    int slot = atomicAdd(&cur[d], 1);
    csr[offs[d] + slot] = s;
}

// ---------------- gather-aggregate (aggregation BEFORE the weight matmul) ----------------
// y[d] = ( sum_{s in in(d)} xrows[row(s)]*coef[s] + xrows[row(d)]*coef[d] ) * rsq[d]
// stage1: coef==rsq, row(s)==s        -> y = A_hat @ x
// stage2: coef[s]=vals[s]*rsq[s], row(s)=perm[s] (physical conv1 row) -> y = A_hat @ (gated sel)
template<bool REMAP>
__launch_bounds__(256)
__global__ void k_agg(const float* xrows, const int* deg, const int* offs, const int* csr,
                      const float* rsq, const float* coef, const int* perm,
                      float* y, int nnodes) {
    int lane = threadIdx.x & 63;
    int node = blockIdx.x * 4 + (threadIdx.x >> 6);
    if (node >= nnodes) return;
    int cnt = deg[node], base = offs[node];
    float acc = 0.0f;
    for (int i = 0; i < cnt; i++) {
        int s = csr[base + i];
        int row = REMAP ? perm[s] : s;
        acc += xrows[(size_t)row * DIM_ + lane] * coef[s];
    }
    int srow = REMAP ? perm[node] : node;
    float self = xrows[(size_t)srow * DIM_ + lane] * coef[node];
    y[(size_t)node * DIM_ + lane] = (acc + self) * rsq[node];
}

// ---------------- fused conv row-matmul + bias + ReLU + score (IN PLACE on y) ----------------
// conv[r] = relu(y[r] @ W + b);  score[r] = tanh(conv[r].p / ||p||)
__launch_bounds__(256)
__global__ void k_convrow(float* y, const float* W, const float* bias, const float* pvec,
                          float* score, int rows) {
    __shared__ float Wl[DIM_ * DIM_];
    __shared__ float bl[DIM_], pl[DIM_];
    __shared__ float rpn;
    int tid = threadIdx.x;
    for (int i = tid; i < DIM_ * DIM_; i += 256) Wl[i] = W[i];
    if (tid < DIM_) { bl[tid] = bias[tid]; pl[tid] = pvec[tid]; }
    __syncthreads();
    if (tid == 0) {
        float s = 0.0f;
        for (int i = 0; i < DIM_; i++) s += pl[i] * pl[i];
        rpn = rsqrtf(s);
    }
    __syncthreads();
    int row = blockIdx.x * 256 + tid;
    if (row >= rows) return;
    float r[DIM_];
    float4* yp = (float4*)(y + (size_t)row * DIM_);
#pragma unroll
    for (int v = 0; v < 16; v++) {
        float4 q = yp[v];
        r[4*v] = q.x; r[4*v+1] = q.y; r[4*v+2] = q.z; r[4*v+3] = q.w;
    }
    float dot = 0.0f;
#pragma unroll
    for (int jb = 0; jb < 16; jb++) {
        float4 acc = make_float4(bl[jb*4], bl[jb*4+1], bl[jb*4+2], bl[jb*4+3]);
#pragma unroll
        for (int i = 0; i < DIM_; i++) {
            float4 w4 = *(const float4*)&Wl[i * DIM_ + jb * 4];
            acc.x += r[i] * w4.x; acc.y += r[i] * w4.y;
            acc.z += r[i] * w4.z; acc.w += r[i] * w4.w;
        }
        acc.x = fmaxf(acc.x, 0.f); acc.y = fmaxf(acc.y, 0.f);
        acc.z = fmaxf(acc.z, 0.f); acc.w = fmaxf(acc.w, 0.f);
        dot += acc.x * pl[jb*4] + acc.y * pl[jb*4+1] + acc.z * pl[jb*4+2] + acc.w * pl[jb*4+3];
        yp[jb] = acc;   // row fully in registers already -> in-place safe
    }
    score[row] = tanhf(dot * rpn);
}

// ---------------- coef[s] = vals[s] * rsq[s] (stage2 gating folded into aggregation) --------
__global__ void k_coef(const float* vals, const float* rsq, float* coef, int n) {
    int i = blockIdx.x * 256 + threadIdx.x;
    if (i < n) coef[i] = vals[i] * rsq[i];
}

// ---------------- per-graph top-k (bitonic sort of packed keys) + fused gated pooling -------
template<int STAGE>
__launch_bounds__(256)
__global__ void k_topk(const float* score, const float* conv, int* new_id, int* perm,
                       float* vals, float* x1, float* hbuf) {
    const int Nin = (STAGE == 1) ? N_ : K1_;
    const int K   = (STAGE == 1) ? K1_ : K2_;
    __shared__ unsigned long long sk[2048];
    __shared__ float red[4][64];
    int g = blockIdx.x;
    int tid = threadIdx.x;
    const float* sg = score + (size_t)g * Nin;

    for (int i = tid; i < 2048; i += 256) {
        unsigned long long key = 0ull;     // padding sorts last (real keys > 0)
        if (i < Nin) {
            unsigned u = __float_as_uint(sg[i]);
            u = (u & 0x80000000u) ? ~u : (u | 0x80000000u);   // order-preserving transform
            key = ((unsigned long long)u << 11) | (unsigned long long)(2047 - i); // ties: low idx first
        }
        sk[i] = key;
    }
    __syncthreads();
    for (int k = 2; k <= 2048; k <<= 1) {             // bitonic sort, descending
        for (int j = k >> 1; j > 0; j >>= 1) {
            for (int i = tid; i < 2048; i += 256) {
                int ixj = i ^ j;
                if (ixj > i) {
                    unsigned long long a = sk[i], b = sk[ixj];
                    bool up = ((i & k) == 0);
                    if (up ? (a < b) : (a > b)) { sk[i] = b; sk[ixj] = a; }
                }
            }
            __syncthreads();
        }
    }
    if (STAGE == 1) {
        for (int jp = tid; jp < 2048; jp += 256) {
            int node = 2047 - (int)(sk[jp] & 0x7FFull);
            int gid = g * N_ + node;
            int nid = (jp < K) ? (g * K + jp) : -1;
            new_id[gid] = nid;
            if (jp < K) {
                perm[g * K + jp] = gid;
                vals[g * K + jp] = sg[node];
            }
        }
        __syncthreads();
    }
    // gated max/mean over kept rows; 4 waves, lane == feature
    int wv = tid >> 6, lane = tid & 63;
    float mx = -3.402823466e38f, sm = 0.0f;
    for (int jp = wv; jp < K; jp += 4) {
        int node = 2047 - (int)(sk[jp] & 0x7FFull);
        float val = sg[node];
        float v = conv[((size_t)g * Nin + node) * DIM_ + lane] * val;
        mx = fmaxf(mx, v);
        sm += v;
    }
    red[wv][lane] = mx;
    __syncthreads();
    if (wv == 0)
        mx = fmaxf(fmaxf(red[0][lane], red[1][lane]), fmaxf(red[2][lane], red[3][lane]));
    __syncthreads();
    red[wv][lane] = sm;
    __syncthreads();
    if (wv == 0) {
        sm = red[0][lane] + red[1][lane] + red[2][lane] + red[3][lane];
        float mean = sm / (float)K;
        if (STAGE == 1) {
            x1[g * 128 + lane]      = mx;
            x1[g * 128 + 64 + lane] = mean;
        } else {
            hbuf[g * 128 + lane]      = x1[g * 128 + lane] + mx;
            hbuf[g * 128 + 64 + lane] = x1[g * 128 + 64 + lane] + mean;
        }
    }
}

// ---------------- MLP head (f32 in, f32 out) ----------------
__launch_bounds__(64)
__global__ void k_head(const float* hbuf, const float* l1w, const float* l1b,
                       const float* l2w, const float* l2b, float* out) {
    __shared__ float h[128];
    __shared__ float h1[64];
    int g = blockIdx.x, t = threadIdx.x;
    h[t]      = hbuf[g * 128 + t];
    h[t + 64] = hbuf[g * 128 + 64 + t];
    __syncthreads();
    float acc = l1b[t];
#pragma unroll 8
    for (int i = 0; i < 128; i++) acc += h[i] * l1w[i * 64 + t];
    h1[t] = fmaxf(acc, 0.0f);
    __syncthreads();
    if (t < NCLS) {
        float o = l2b[t];
#pragma unroll
        for (int i = 0; i < 64; i++) o += h1[i] * l2w[i * NCLS + t];
        out[g * NCLS + t] = o;
    }
}

extern "C" void kernel_launch(void* const* d_in, const int* in_sizes, int n_in,
                              void* d_out, int out_size, void* d_ws, size_t ws_size,
                              hipStream_t stream) {
    // ALL float tensors are float32 per the reference (only edge_index/batch are int32)
    const float* x   = (const float*)d_in[0];
    const int*   ei  = (const int*)d_in[1];
    const int*   src = ei;
    const int*   dst = ei + ETOT;
    const float* W1  = (const float*)d_in[3];
    const float* b1  = (const float*)d_in[4];
    const float* p1  = (const float*)d_in[5];
    const float* W2  = (const float*)d_in[6];
    const float* b2  = (const float*)d_in[7];
    const float* p2  = (const float*)d_in[8];
    const float* l1w = (const float*)d_in[9];
    const float* l1b = (const float*)d_in[10];
    const float* l2w = (const float*)d_in[11];
    const float* l2b = (const float*)d_in[12];
    (void)in_sizes; (void)n_in; (void)out_size; (void)ws_size;

    // workspace layout (~73 MB)
    char* ws = (char*)d_ws;
    size_t off = 0;
    auto alloc = [&](size_t bytes) -> void* {
        void* p = ws + off;
        off = (off + bytes + 255) & ~(size_t)255;
        return p;
    };
    float* bufA  = (float*)alloc((size_t)NTOT  * DIM_ * 4);  // y1 -> conv1 (in place)
    float* bufB  = (float*)alloc((size_t)N2TOT * DIM_ * 4);  // y2 -> conv2 (in place)
    int*   csr   = (int*)  alloc((size_t)ETOT * 4);
    int*   deg   = (int*)  alloc((size_t)NTOT * 4);
    int*   offs  = (int*)  alloc((size_t)NTOT * 4);
    int*   cur   = (int*)  alloc((size_t)NTOT * 4);
    float* rsq   = (float*)alloc((size_t)NTOT * 4);
    float* score = (float*)alloc((size_t)NTOT * 4);
    int*   newid = (int*)  alloc((size_t)NTOT * 4);
    float* coef  = (float*)alloc((size_t)N2TOT * 4);
    int*   perm  = (int*)  alloc((size_t)N2TOT * 4);
    float* vals  = (float*)alloc((size_t)N2TOT * 4);
    float* x1    = (float*)alloc((size_t)B_ * 128 * 4);
    float* hbuf  = (float*)alloc((size_t)B_ * 128 * 4);

    // ---- stage 1 ----
    k_zero<<<NTOT / 256, 256, 0, stream>>>(deg, NTOT);
    k_count<false><<<ETOT / 256, 256, 0, stream>>>(src, dst, nullptr, deg);
    k_scan<N_><<<B_, 256, 0, stream>>>(deg, offs, cur, rsq);
    k_fill<false><<<ETOT / 256, 256, 0, stream>>>(src, dst, nullptr, offs, cur, csr);
    k_agg<false><<<NTOT / 4, 256, 0, stream>>>(x, deg, offs, csr, rsq, rsq, nullptr, bufA, NTOT);
    k_convrow<<<NTOT / 256, 256, 0, stream>>>(bufA, W1, b1, p1, score, NTOT);
    k_topk<1><<<B_, 256, 0, stream>>>(score, bufA, newid, perm, vals, x1, nullptr);

    // ---- stage 2 ----
    k_zero<<<(N2TOT + 255) / 256, 256, 0, stream>>>(deg, N2TOT);
    k_count<true><<<ETOT / 256, 256, 0, stream>>>(src, dst, newid, deg);
    k_scan<K1_><<<B_, 256, 0, stream>>>(deg, offs, cur, rsq);
    k_coef<<<(N2TOT + 255) / 256, 256, 0, stream>>>(vals, rsq, coef, N2TOT);
    k_fill<true><<<ETOT / 256, 256, 0, stream>>>(src, dst, newid, offs, cur, csr);
    k_agg<true><<<(N2TOT + 3) / 4, 256, 0, stream>>>(bufA, deg, offs, csr, rsq, coef, perm, bufB, N2TOT);
    k_convrow<<<(N2TOT + 255) / 256, 256, 0, stream>>>(bufB, W2, b2, p2, score, N2TOT);
    k_topk<2><<<B_, 256, 0, stream>>>(score, bufB, nullptr, nullptr, nullptr, x1, hbuf);

    // ---- head ----
    k_head<<<B_, 64, 0, stream>>>(hbuf, l1w, l1b, l2w, l2b, (float*)d_out);
}

// Round 4
// 805.590 us; speedup vs baseline: 1.4723x; 1.4723x over previous
//
#include <hip/hip_runtime.h>
#include <hip/hip_bf16.h>
#include <cstdint>
#include <cstddef>

#define B_    64
#define N_    2048
#define E_    32768            // edges per graph
#define DIM_  64
#define K1_   1639
#define K2_   1312
#define NTOT  (B_ * N_)        // 131072
#define ETOT  (B_ * E_)        // 2097152
#define N2TOT (B_ * K1_)       // 104896
#define NCLS  6
#define PB_   8                // pooling blocks per graph

// ---------------- zero an int array ----------------
__global__ void k_zero(int* a, int n) {
    int i = blockIdx.x * 256 + threadIdx.x;
    if (i < n) a[i] = 0;
}

// ---------------- in-degree count (int atomics only) ----------------
template<bool REMAP>
__global__ void k_count(const int* src, const int* dst, const int* remap, int* deg) {
    int e = blockIdx.x * 256 + threadIdx.x;   // grid is exactly ETOT/256
    int d = dst[e];
    if (REMAP) {
        int s = remap[src[e]];
        d = remap[d];
        if ((s | d) < 0) return;              // edge touches a dropped node
    }
    atomicAdd(&deg[d], 1);
}

// ---------------- per-graph exclusive scan of deg -> CSR offsets ----------------
template<int NLOC>
__launch_bounds__(256)
__global__ void k_scan(const int* deg, int* offs, int* cur, float* rsq) {
    __shared__ int ts[256];
    const int PER = (NLOC + 255) / 256;
    int g = blockIdx.x, tid = threadIdx.x;
    int c[PER];
    int s = 0;
#pragma unroll
    for (int i = 0; i < PER; i++) {
        int idx = tid * PER + i;
        c[i] = (idx < NLOC) ? deg[g * NLOC + idx] : 0;
        s += c[i];
    }
    ts[tid] = s;
    __syncthreads();
    for (int o = 1; o < 256; o <<= 1) {
        int v = (tid >= o) ? ts[tid - o] : 0;
        __syncthreads();
        ts[tid] += v;
        __syncthreads();
    }
    int run = ts[tid] - s + g * E_;
#pragma unroll
    for (int i = 0; i < PER; i++) {
        int idx = tid * PER + i;
        if (idx < NLOC) {
            int node = g * NLOC + idx;
            offs[node] = run;
            cur[node] = 0;
            rsq[node] = rsqrtf((float)(c[i] + 1));
            run += c[i];
        }
    }
}

// ---------------- CSR fill: csr[offs[d] + slot] = s ----------------
template<bool REMAP>
__global__ void k_fill(const int* src, const int* dst, const int* remap,
                       const int* offs, int* cur, int* csr) {
    int e = blockIdx.x * 256 + threadIdx.x;
    int s = src[e], d = dst[e];
    if (REMAP) {
        s = remap[s]; d = remap[d];
        if ((s | d) < 0) return;
    }
    int slot = atomicAdd(&cur[d], 1);
    csr[offs[d] + slot] = s;
}

// ---------------- gather-aggregate (aggregation BEFORE the weight matmul) ----------------
// y[d] = ( sum_{s in in(d)} xrows[row(s)]*c(s) + xrows[row(d)]*c(d) ) * rsq[d]
// GATE=false: row(s)=s,      c(s)=rsq[s]
// GATE=true : row(s)=sel[s], c(s)=gatev[s]*rsq[s]   (TopK gating folded in)
// wave per node; cooperative CSR load + shuffle broadcast; 4-way unrolled gathers
template<bool GATE>
__launch_bounds__(256)
__global__ void k_agg(const float* xrows, const int* deg, const int* offs, const int* csr,
                      const float* rsq, const float* gatev, const int* sel,
                      float* y, int nnodes) {
    int lane = threadIdx.x & 63;
    int node = blockIdx.x * 4 + (threadIdx.x >> 6);
    if (node >= nnodes) return;
    int cnt = deg[node];
    int base = offs[node];
    float a0 = 0.f, a1 = 0.f, a2 = 0.f, a3 = 0.f;
    for (int chunk = 0; chunk < cnt; chunk += 64) {
        int nch = min(64, cnt - chunk);
        int sv = 0; float cv = 0.f;
        if (lane < nch) {
            int s = csr[base + chunk + lane];
            sv = GATE ? sel[s] : s;
            cv = GATE ? (gatev[s] * rsq[s]) : rsq[s];
        }
        int i = 0;
        for (; i + 4 <= nch; i += 4) {
            int   r0 = __shfl(sv, i),   r1 = __shfl(sv, i+1),
                  r2 = __shfl(sv, i+2), r3 = __shfl(sv, i+3);
            float c0 = __shfl(cv, i),   c1 = __shfl(cv, i+1),
                  c2 = __shfl(cv, i+2), c3 = __shfl(cv, i+3);
            float v0 = xrows[(size_t)r0 * DIM_ + lane];
            float v1 = xrows[(size_t)r1 * DIM_ + lane];
            float v2 = xrows[(size_t)r2 * DIM_ + lane];
            float v3 = xrows[(size_t)r3 * DIM_ + lane];
            a0 += v0 * c0; a1 += v1 * c1; a2 += v2 * c2; a3 += v3 * c3;
        }
        for (; i < nch; i++) {
            int r = __shfl(sv, i); float c = __shfl(cv, i);
            a0 += xrows[(size_t)r * DIM_ + lane] * c;
        }
    }
    int snode = GATE ? sel[node] : node;
    float scf = GATE ? (gatev[node] * rsq[node]) : rsq[node];
    a0 += xrows[(size_t)snode * DIM_ + lane] * scf;
    y[(size_t)node * DIM_ + lane] = ((a0 + a1) + (a2 + a3)) * rsq[node];
}

// ---------------- fused conv row-matmul + bias + ReLU + score (IN PLACE on y) ----------------
__launch_bounds__(256)
__global__ void k_convrow(float* y, const float* W, const float* bias, const float* pvec,
                          float* score, int rows) {
    __shared__ float Wl[DIM_ * DIM_];
    __shared__ float bl[DIM_], pl[DIM_];
    __shared__ float rpn;
    int tid = threadIdx.x;
    for (int i = tid; i < DIM_ * DIM_; i += 256) Wl[i] = W[i];
    if (tid < DIM_) { bl[tid] = bias[tid]; pl[tid] = pvec[tid]; }
    __syncthreads();
    if (tid == 0) {
        float s = 0.0f;
        for (int i = 0; i < DIM_; i++) s += pl[i] * pl[i];
        rpn = rsqrtf(s);
    }
    __syncthreads();
    int row = blockIdx.x * 256 + tid;
    if (row >= rows) return;
    float r[DIM_];
    float4* yp = (float4*)(y + (size_t)row * DIM_);
#pragma unroll
    for (int v = 0; v < 16; v++) {
        float4 q = yp[v];
        r[4*v] = q.x; r[4*v+1] = q.y; r[4*v+2] = q.z; r[4*v+3] = q.w;
    }
    float dot = 0.0f;
#pragma unroll
    for (int jb = 0; jb < 16; jb++) {
        float4 acc = make_float4(bl[jb*4], bl[jb*4+1], bl[jb*4+2], bl[jb*4+3]);
#pragma unroll
        for (int i = 0; i < DIM_; i++) {
            float4 w4 = *(const float4*)&Wl[i * DIM_ + jb * 4];
            acc.x += r[i] * w4.x; acc.y += r[i] * w4.y;
            acc.z += r[i] * w4.z; acc.w += r[i] * w4.w;
        }
        acc.x = fmaxf(acc.x, 0.f); acc.y = fmaxf(acc.y, 0.f);
        acc.z = fmaxf(acc.z, 0.f); acc.w = fmaxf(acc.w, 0.f);
        dot += acc.x * pl[jb*4] + acc.y * pl[jb*4+1] + acc.z * pl[jb*4+2] + acc.w * pl[jb*4+3];
        yp[jb] = acc;
    }
    score[row] = tanhf(dot * rpn);
}

// ---------------- exact top-K selection via 6-pass radix select on packed keys ----------------
// key = (orderable(score) << 11) | (2047 - idx)  -> all distinct, ties broken low-idx-first.
// Emits kept set with ARBITRARY rank order (output-invariant; see notes).
template<int STAGE>
__launch_bounds__(256)
__global__ void k_select(const float* score, int* new_id, int* sel, float* vals) {
    const int Nin = (STAGE == 1) ? N_ : K1_;
    const int K   = (STAGE == 1) ? K1_ : K2_;
    __shared__ unsigned long long keys[N_];
    __shared__ int bins[256];
    __shared__ unsigned long long s_prefix;
    __shared__ int s_need, s_cnt;
    int g = blockIdx.x, tid = threadIdx.x;
    const float* sg = score + (size_t)g * Nin;
    for (int i = tid; i < Nin; i += 256) {
        unsigned u = __float_as_uint(sg[i]);
        u = (u & 0x80000000u) ? ~u : (u | 0x80000000u);
        keys[i] = ((unsigned long long)u << 11) | (unsigned long long)(2047 - i);
    }
    if (tid == 0) { s_need = K; s_prefix = 0ull; s_cnt = 0; }
    __syncthreads();
    for (int shift = 40; shift >= 0; shift -= 8) {
        bins[tid] = 0;
        __syncthreads();
        unsigned long long pref = s_prefix;
        int hi = shift + 8;
        for (int i = tid; i < Nin; i += 256) {
            unsigned long long k = keys[i];
            if ((k >> hi) == pref) atomicAdd(&bins[(int)((k >> shift) & 255)], 1);
        }
        __syncthreads();
        if (tid == 0) {
            int need = s_need, cum = 0, d = 255;
            for (; d > 0; d--) { cum += bins[d]; if (cum >= need) break; }
            if (cum < need) cum += bins[0];           // d==0 fallthrough
            s_need = need - (cum - bins[d]);
            s_prefix = (pref << 8) | (unsigned long long)d;
        }
        __syncthreads();
    }
    unsigned long long T = s_prefix;   // exact K-th largest key
    for (int i = tid; i < Nin; i += 256) {
        if (keys[i] >= T) {
            int r = atomicAdd(&s_cnt, 1);
            int slot = g * K + r;
            sel[slot]  = g * Nin + i;   // node id in this stage's index space
            vals[slot] = sg[i];
            if (STAGE == 1) new_id[g * N_ + i] = slot;
        } else if (STAGE == 1) {
            new_id[g * N_ + i] = -1;
        }
    }
}

// ---------------- gated max/mean pooling, PB_ blocks per graph ----------------
template<int STAGE>
__launch_bounds__(256)
__global__ void k_pool(const float* conv, const int* sel, const float* vals, float* part) {
    const int K = (STAGE == 1) ? K1_ : K2_;
    int g = blockIdx.x / PB_, c = blockIdx.x % PB_;
    int wv = threadIdx.x >> 6, lane = threadIdx.x & 63;
    float mx = -3.402823466e38f, sm = 0.f;
    for (int r = c * 4 + wv; r < K; r += PB_ * 4) {
        int slot = g * K + r;
        int row  = sel[slot];
        float val = vals[slot];
        float v = conv[(size_t)row * DIM_ + lane] * val;
        mx = fmaxf(mx, v);
        sm += v;
    }
    __shared__ float rmx[4][64], rsm[4][64];
    rmx[wv][lane] = mx; rsm[wv][lane] = sm;
    __syncthreads();
    if (wv == 0) {
        mx = fmaxf(fmaxf(rmx[0][lane], rmx[1][lane]), fmaxf(rmx[2][lane], rmx[3][lane]));
        sm = rsm[0][lane] + rsm[1][lane] + rsm[2][lane] + rsm[3][lane];
        part[((size_t)(g * PB_ + c) * 2 + 0) * 64 + lane] = mx;
        part[((size_t)(g * PB_ + c) * 2 + 1) * 64 + lane] = sm;
    }
}

// ---------------- combine partials -> x1 (stage1) or hbuf = x1 + x2 (stage2) ----------------
template<int STAGE>
__launch_bounds__(64)
__global__ void k_comb(const float* part, float* x1, float* hbuf) {
    const int K = (STAGE == 1) ? K1_ : K2_;
    int g = blockIdx.x, lane = threadIdx.x;
    float mx = -3.402823466e38f, sm = 0.f;
    for (int c = 0; c < PB_; c++) {
        mx = fmaxf(mx, part[((size_t)(g * PB_ + c) * 2 + 0) * 64 + lane]);
        sm += part[((size_t)(g * PB_ + c) * 2 + 1) * 64 + lane];
    }
    float mean = sm / (float)K;
    if (STAGE == 1) {
        x1[g * 128 + lane]      = mx;
        x1[g * 128 + 64 + lane] = mean;
    } else {
        hbuf[g * 128 + lane]      = x1[g * 128 + lane] + mx;
        hbuf[g * 128 + 64 + lane] = x1[g * 128 + 64 + lane] + mean;
    }
}

// ---------------- MLP head ----------------
__launch_bounds__(64)
__global__ void k_head(const float* hbuf, const float* l1w, const float* l1b,
                       const float* l2w, const float* l2b, float* out) {
    __shared__ float h[128];
    __shared__ float h1[64];
    int g = blockIdx.x, t = threadIdx.x;
    h[t]      = hbuf[g * 128 + t];
    h[t + 64] = hbuf[g * 128 + 64 + t];
    __syncthreads();
    float acc = l1b[t];
#pragma unroll 8
    for (int i = 0; i < 128; i++) acc += h[i] * l1w[i * 64 + t];
    h1[t] = fmaxf(acc, 0.0f);
    __syncthreads();
    if (t < NCLS) {
        float o = l2b[t];
#pragma unroll
        for (int i = 0; i < 64; i++) o += h1[i] * l2w[i * NCLS + t];
        out[g * NCLS + t] = o;
    }
}

extern "C" void kernel_launch(void* const* d_in, const int* in_sizes, int n_in,
                              void* d_out, int out_size, void* d_ws, size_t ws_size,
                              hipStream_t stream) {
    const float* x   = (const float*)d_in[0];
    const int*   ei  = (const int*)d_in[1];
    const int*   src = ei;
    const int*   dst = ei + ETOT;
    const float* W1  = (const float*)d_in[3];
    const float* b1  = (const float*)d_in[4];
    const float* p1  = (const float*)d_in[5];
    const float* W2  = (const float*)d_in[6];
    const float* b2  = (const float*)d_in[7];
    const float* p2  = (const float*)d_in[8];
    const float* l1w = (const float*)d_in[9];
    const float* l1b = (const float*)d_in[10];
    const float* l2w = (const float*)d_in[11];
    const float* l2b = (const float*)d_in[12];
    (void)in_sizes; (void)n_in; (void)out_size; (void)ws_size;

    char* ws = (char*)d_ws;
    size_t off = 0;
    auto alloc = [&](size_t bytes) -> void* {
        void* p = ws + off;
        off = (off + bytes + 255) & ~(size_t)255;
        return p;
    };
    float* bufA  = (float*)alloc((size_t)NTOT  * DIM_ * 4);  // y1 -> conv1 (in place)
    float* bufB  = (float*)alloc((size_t)N2TOT * DIM_ * 4);  // y2 -> conv2 (in place)
    int*   csr   = (int*)  alloc((size_t)ETOT * 4);
    int*   deg   = (int*)  alloc((size_t)NTOT * 4);
    int*   offs  = (int*)  alloc((size_t)NTOT * 4);
    int*   cur   = (int*)  alloc((size_t)NTOT * 4);
    float* rsq   = (float*)alloc((size_t)NTOT * 4);
    float* score = (float*)alloc((size_t)NTOT * 4);
    int*   newid = (int*)  alloc((size_t)NTOT * 4);
    int*   sel1  = (int*)  alloc((size_t)N2TOT * 4);
    float* vals1 = (float*)alloc((size_t)N2TOT * 4);
    int*   sel2  = (int*)  alloc((size_t)B_ * K2_ * 4);
    float* vals2 = (float*)alloc((size_t)B_ * K2_ * 4);
    float* part  = (float*)alloc((size_t)B_ * PB_ * 128 * 4);
    float* x1    = (float*)alloc((size_t)B_ * 128 * 4);
    float* hbuf  = (float*)alloc((size_t)B_ * 128 * 4);

    // ---- stage 1 ----
    k_zero<<<NTOT / 256, 256, 0, stream>>>(deg, NTOT);
    k_count<false><<<ETOT / 256, 256, 0, stream>>>(src, dst, nullptr, deg);
    k_scan<N_><<<B_, 256, 0, stream>>>(deg, offs, cur, rsq);
    k_fill<false><<<ETOT / 256, 256, 0, stream>>>(src, dst, nullptr, offs, cur, csr);
    k_agg<false><<<NTOT / 4, 256, 0, stream>>>(x, deg, offs, csr, rsq, nullptr, nullptr, bufA, NTOT);
    k_convrow<<<NTOT / 256, 256, 0, stream>>>(bufA, W1, b1, p1, score, NTOT);
    k_select<1><<<B_, 256, 0, stream>>>(score, newid, sel1, vals1);
    k_pool<1><<<B_ * PB_, 256, 0, stream>>>(bufA, sel1, vals1, part);
    k_comb<1><<<B_, 64, 0, stream>>>(part, x1, nullptr);

    // ---- stage 2 ----
    k_zero<<<(N2TOT + 255) / 256, 256, 0, stream>>>(deg, N2TOT);
    k_count<true><<<ETOT / 256, 256, 0, stream>>>(src, dst, newid, deg);
    k_scan<K1_><<<B_, 256, 0, stream>>>(deg, offs, cur, rsq);
    k_fill<true><<<ETOT / 256, 256, 0, stream>>>(src, dst, newid, offs, cur, csr);
    k_agg<true><<<(N2TOT + 3) / 4, 256, 0, stream>>>(bufA, deg, offs, csr, rsq, vals1, sel1, bufB, N2TOT);
    k_convrow<<<(N2TOT + 255) / 256, 256, 0, stream>>>(bufB, W2, b2, p2, score, N2TOT);
    k_select<2><<<B_, 256, 0, stream>>>(score, nullptr, sel2, vals2);
    k_pool<2><<<B_ * PB_, 256, 0, stream>>>(bufB, sel2, vals2, part);
    k_comb<2><<<B_, 64, 0, stream>>>(part, x1, hbuf);

    // ---- head ----
    k_head<<<B_, 64, 0, stream>>>(hbuf, l1w, l1b, l2w, l2b, (float*)d_out);
}

// Round 5
// 545.047 us; speedup vs baseline: 2.1761x; 1.4780x over previous
//
#include <hip/hip_runtime.h>
#include <hip/hip_bf16.h>
#include <cstdint>
#include <cstddef>

#define B_    64
#define N_    2048
#define E_    32768            // edges per graph
#define DIM_  64
#define K1_   1639
#define K2_   1312
#define NTOT  (B_ * N_)        // 131072
#define ETOT  (B_ * E_)        // 2097152
#define N2TOT (B_ * K1_)       // 104896
#define NCLS  6
#define PB_   8                // pooling blocks per graph
#define CSTRIDE 64             // CSR slots per node (max in-degree; Poisson(16) tail @64 ~ 1e-14)

// ---------------- zero an int array ----------------
__global__ void k_zero(int* a, int n) {
    int i = blockIdx.x * 256 + threadIdx.x;
    if (i < n) a[i] = 0;
}

// ---------------- direct CSR fill, fixed stride, per-graph-local ushort src ids -------------
template<bool REMAP>
__global__ void k_fill(const int* src, const int* dst, const int* remap,
                       int* deg, unsigned short* csr) {
    int e = blockIdx.x * 256 + threadIdx.x;   // grid exactly ETOT/256
    int s = src[e], d = dst[e];
    if (REMAP) {
        s = remap[s]; d = remap[d];
        if ((s | d) < 0) return;              // edge touches a dropped node
    }
    int base = REMAP ? (d / K1_) * K1_ : (d & ~(N_ - 1));   // graph base in this id space
    int slot = atomicAdd(&deg[d], 1);
    if (slot < CSTRIDE) csr[(size_t)d * CSTRIDE + slot] = (unsigned short)(s - base);
}

// ---------------- rsq[i]=rsqrt(deg+1); coef[i]=vals[i]*rsq[i] (stage2 gating) ---------------
template<bool GATE>
__global__ void k_rsq(const int* deg, const float* vals, float* rsq, float* coef, int n) {
    int i = blockIdx.x * 256 + threadIdx.x;
    if (i >= n) return;
    float rv = rsqrtf((float)(deg[i] + 1));
    rsq[i] = rv;
    if (GATE) coef[i] = vals[i] * rv;
}

// ---------------- gather-aggregate, XCD-swizzled (graph-clustered per XCD) ------------------
// y[d] = ( sum_{s in in(d)} xrows[row(s)]*coef[s] + xrows[row(d)]*coef[d] ) * rsq[d]
// GATE=false: row(s)=s (coef==rsq).  GATE=true: row(s)=sel[s] (stage-1 physical row).
template<bool GATE>
__launch_bounds__(256)
__global__ void k_agg(const float* xrows, const int* deg, const unsigned short* csr,
                      const float* rsq, const float* coef, const int* sel, float* y) {
    int b = blockIdx.x;
    int xcd = b & 7, r = b >> 3;
    int graph, local;
    if (GATE) {
        graph = xcd * 8 + r / 410;            // 410 blocks/graph (ceil(1639/4))
        local = (r % 410) * 4 + (threadIdx.x >> 6);
        if (local >= K1_) return;
    } else {
        graph = xcd * 8 + (r >> 9);           // 512 blocks/graph
        local = (r & 511) * 4 + (threadIdx.x >> 6);
    }
    const int NL = GATE ? K1_ : N_;
    int node = graph * NL + local;
    int lane = threadIdx.x & 63;
    int cnt = deg[node];                       // < CSTRIDE by construction
    const unsigned short* cp = csr + (size_t)node * CSTRIDE;
    int sv = 0; float cv = 0.f;
    if (lane < cnt) {
        int s = graph * NL + (int)cp[lane];
        sv = GATE ? sel[s] : s;
        cv = coef[s];
    }
    float a0 = 0.f, a1 = 0.f, a2 = 0.f, a3 = 0.f;
    int i = 0;
    for (; i + 4 <= cnt; i += 4) {
        int   r0 = __shfl(sv, i),   r1 = __shfl(sv, i+1),
              r2 = __shfl(sv, i+2), r3 = __shfl(sv, i+3);
        float c0 = __shfl(cv, i),   c1 = __shfl(cv, i+1),
              c2 = __shfl(cv, i+2), c3 = __shfl(cv, i+3);
        a0 += xrows[(size_t)r0 * DIM_ + lane] * c0;
        a1 += xrows[(size_t)r1 * DIM_ + lane] * c1;
        a2 += xrows[(size_t)r2 * DIM_ + lane] * c2;
        a3 += xrows[(size_t)r3 * DIM_ + lane] * c3;
    }
    for (; i < cnt; i++) {
        int rr = __shfl(sv, i); float cc = __shfl(cv, i);
        a0 += xrows[(size_t)rr * DIM_ + lane] * cc;
    }
    int snode = GATE ? sel[node] : node;
    a0 += xrows[(size_t)snode * DIM_ + lane] * coef[node];
    y[(size_t)node * DIM_ + lane] = ((a0 + a1) + (a2 + a3)) * rsq[node];
}

// ---------------- fused conv row-matmul + bias + ReLU + score (IN PLACE on y) ---------------
__launch_bounds__(256)
__global__ void k_convrow(float* y, const float* W, const float* bias, const float* pvec,
                          float* score, int rows) {
    __shared__ float Wl[DIM_ * DIM_];
    __shared__ float bl[DIM_], pl[DIM_];
    __shared__ float rpn;
    int tid = threadIdx.x;
    for (int i = tid; i < DIM_ * DIM_; i += 256) Wl[i] = W[i];
    if (tid < DIM_) { bl[tid] = bias[tid]; pl[tid] = pvec[tid]; }
    __syncthreads();
    if (tid == 0) {
        float s = 0.0f;
        for (int i = 0; i < DIM_; i++) s += pl[i] * pl[i];
        rpn = rsqrtf(s);
    }
    __syncthreads();
    int row = blockIdx.x * 256 + tid;
    if (row >= rows) return;
    float r[DIM_];
    float4* yp = (float4*)(y + (size_t)row * DIM_);
#pragma unroll
    for (int v = 0; v < 16; v++) {
        float4 q = yp[v];
        r[4*v] = q.x; r[4*v+1] = q.y; r[4*v+2] = q.z; r[4*v+3] = q.w;
    }
    float dot = 0.0f;
#pragma unroll
    for (int jb = 0; jb < 16; jb++) {
        float4 acc = make_float4(bl[jb*4], bl[jb*4+1], bl[jb*4+2], bl[jb*4+3]);
#pragma unroll
        for (int i = 0; i < DIM_; i++) {
            float4 w4 = *(const float4*)&Wl[i * DIM_ + jb * 4];
            acc.x += r[i] * w4.x; acc.y += r[i] * w4.y;
            acc.z += r[i] * w4.z; acc.w += r[i] * w4.w;
        }
        acc.x = fmaxf(acc.x, 0.f); acc.y = fmaxf(acc.y, 0.f);
        acc.z = fmaxf(acc.z, 0.f); acc.w = fmaxf(acc.w, 0.f);
        dot += acc.x * pl[jb*4] + acc.y * pl[jb*4+1] + acc.z * pl[jb*4+2] + acc.w * pl[jb*4+3];
        yp[jb] = acc;
    }
    score[row] = tanhf(dot * rpn);
}

// ---------------- exact top-K: 6-pass radix select, PARALLEL suffix-sum bin scan ------------
// key = (orderable(score) << 11) | (2047-idx): distinct keys, ties -> low idx first.
template<int STAGE>
__launch_bounds__(256)
__global__ void k_select(const float* score, int* new_id, int* sel, float* vals) {
    const int Nin = (STAGE == 1) ? N_ : K1_;
    const int K   = (STAGE == 1) ? K1_ : K2_;
    __shared__ unsigned long long keys[N_];
    __shared__ int bins[256], ts[256];
    __shared__ unsigned long long s_prefix;
    __shared__ int s_need, s_cnt;
    int g = blockIdx.x, tid = threadIdx.x;
    const float* sg = score + (size_t)g * Nin;
    for (int i = tid; i < Nin; i += 256) {
        unsigned u = __float_as_uint(sg[i]);
        u = (u & 0x80000000u) ? ~u : (u | 0x80000000u);
        keys[i] = ((unsigned long long)u << 11) | (unsigned long long)(2047 - i);
    }
    if (tid == 0) { s_need = K; s_prefix = 0ull; s_cnt = 0; }
    __syncthreads();
    for (int shift = 40; shift >= 0; shift -= 8) {
        bins[tid] = 0;
        __syncthreads();
        unsigned long long pref = s_prefix;
        int need = s_need;
        int hi = shift + 8;
        for (int i = tid; i < Nin; i += 256) {
            unsigned long long k = keys[i];
            if ((k >> hi) == pref) atomicAdd(&bins[(int)((k >> shift) & 255)], 1);
        }
        __syncthreads();
        ts[tid] = bins[tid];
        __syncthreads();
        for (int o = 1; o < 256; o <<= 1) {      // suffix sum: ts[d] = sum_{j>=d} bins[j]
            int add = (tid + o < 256) ? ts[tid + o] : 0;
            __syncthreads();
            ts[tid] += add;
            __syncthreads();
        }
        int nxt = (tid == 255) ? 0 : ts[tid + 1];
        if (ts[tid] >= need && nxt < need) {     // exactly one tid matches (ts non-increasing)
            s_prefix = (pref << 8) | (unsigned long long)tid;
            s_need = need - nxt;
        }
        __syncthreads();
    }
    unsigned long long T = s_prefix;             // exact K-th largest key
    for (int i = tid; i < Nin; i += 256) {
        if (keys[i] >= T) {
            int r = atomicAdd(&s_cnt, 1);
            int slot = g * K + r;
            sel[slot]  = g * Nin + i;            // node id in this stage's index space
            vals[slot] = sg[i];
            if (STAGE == 1) new_id[g * N_ + i] = slot;
        } else if (STAGE == 1) {
            new_id[g * N_ + i] = -1;
        }
    }
}

// ---------------- gated max/mean pooling, PB_ blocks per graph (XCD-swizzled) ---------------
template<int STAGE>
__launch_bounds__(256)
__global__ void k_pool(const float* conv, const int* sel, const float* vals, float* part) {
    const int K = (STAGE == 1) ? K1_ : K2_;
    int b = blockIdx.x;
    int xcd = b & 7, t = b >> 3;
    int g = xcd * 8 + (t >> 3), c = t & 7;
    int wv = threadIdx.x >> 6, lane = threadIdx.x & 63;
    float mx = -3.402823466e38f, sm = 0.f;
    for (int r = c * 4 + wv; r < K; r += PB_ * 4) {
        int slot = g * K + r;
        int row  = sel[slot];
        float val = vals[slot];
        float v = conv[(size_t)row * DIM_ + lane] * val;
        mx = fmaxf(mx, v);
        sm += v;
    }
    __shared__ float rmx[4][64], rsm[4][64];
    rmx[wv][lane] = mx; rsm[wv][lane] = sm;
    __syncthreads();
    if (wv == 0) {
        mx = fmaxf(fmaxf(rmx[0][lane], rmx[1][lane]), fmaxf(rmx[2][lane], rmx[3][lane]));
        sm = rsm[0][lane] + rsm[1][lane] + rsm[2][lane] + rsm[3][lane];
        part[((size_t)(g * PB_ + c) * 2 + 0) * 64 + lane] = mx;
        part[((size_t)(g * PB_ + c) * 2 + 1) * 64 + lane] = sm;
    }
}

// ---------------- combine partials -> x1 (stage1) or hbuf = x1 + x2 (stage2) ----------------
template<int STAGE>
__launch_bounds__(64)
__global__ void k_comb(const float* part, float* x1, float* hbuf) {
    const int K = (STAGE == 1) ? K1_ : K2_;
    int g = blockIdx.x, lane = threadIdx.x;
    float mx = -3.402823466e38f, sm = 0.f;
    for (int c = 0; c < PB_; c++) {
        mx = fmaxf(mx, part[((size_t)(g * PB_ + c) * 2 + 0) * 64 + lane]);
        sm += part[((size_t)(g * PB_ + c) * 2 + 1) * 64 + lane];
    }
    float mean = sm / (float)K;
    if (STAGE == 1) {
        x1[g * 128 + lane]      = mx;
        x1[g * 128 + 64 + lane] = mean;
    } else {
        hbuf[g * 128 + lane]      = x1[g * 128 + lane] + mx;
        hbuf[g * 128 + 64 + lane] = x1[g * 128 + 64 + lane] + mean;
    }
}

// ---------------- MLP head ----------------
__launch_bounds__(64)
__global__ void k_head(const float* hbuf, const float* l1w, const float* l1b,
                       const float* l2w, const float* l2b, float* out) {
    __shared__ float h[128];
    __shared__ float h1[64];
    int g = blockIdx.x, t = threadIdx.x;
    h[t]      = hbuf[g * 128 + t];
    h[t + 64] = hbuf[g * 128 + 64 + t];
    __syncthreads();
    float acc = l1b[t];
#pragma unroll 8
    for (int i = 0; i < 128; i++) acc += h[i] * l1w[i * 64 + t];
    h1[t] = fmaxf(acc, 0.0f);
    __syncthreads();
    if (t < NCLS) {
        float o = l2b[t];
#pragma unroll
        for (int i = 0; i < 64; i++) o += h1[i] * l2w[i * NCLS + t];
        out[g * NCLS + t] = o;
    }
}

extern "C" void kernel_launch(void* const* d_in, const int* in_sizes, int n_in,
                              void* d_out, int out_size, void* d_ws, size_t ws_size,
                              hipStream_t stream) {
    const float* x   = (const float*)d_in[0];
    const int*   ei  = (const int*)d_in[1];
    const int*   src = ei;
    const int*   dst = ei + ETOT;
    const float* W1  = (const float*)d_in[3];
    const float* b1  = (const float*)d_in[4];
    const float* p1  = (const float*)d_in[5];
    const float* W2  = (const float*)d_in[6];
    const float* b2  = (const float*)d_in[7];
    const float* p2  = (const float*)d_in[8];
    const float* l1w = (const float*)d_in[9];
    const float* l1b = (const float*)d_in[10];
    const float* l2w = (const float*)d_in[11];
    const float* l2b = (const float*)d_in[12];
    (void)in_sizes; (void)n_in; (void)out_size; (void)ws_size;

    // workspace layout (~82 MB)
    char* ws = (char*)d_ws;
    size_t off = 0;
    auto alloc = [&](size_t bytes) -> void* {
        void* p = ws + off;
        off = (off + bytes + 255) & ~(size_t)255;
        return p;
    };
    float*          bufA  = (float*)         alloc((size_t)NTOT  * DIM_ * 4); // y1 -> conv1
    float*          bufB  = (float*)         alloc((size_t)N2TOT * DIM_ * 4); // y2 -> conv2
    unsigned short* csr   = (unsigned short*)alloc((size_t)NTOT * CSTRIDE * 2);
    int*            deg   = (int*)           alloc((size_t)NTOT * 4);
    float*          rsq   = (float*)         alloc((size_t)NTOT * 4);
    float*          coef  = (float*)         alloc((size_t)N2TOT * 4);
    float*          score = (float*)         alloc((size_t)NTOT * 4);
    int*            newid = (int*)           alloc((size_t)NTOT * 4);
    int*            sel1  = (int*)           alloc((size_t)N2TOT * 4);
    float*          vals1 = (float*)         alloc((size_t)N2TOT * 4);
    int*            sel2  = (int*)           alloc((size_t)B_ * K2_ * 4);
    float*          vals2 = (float*)         alloc((size_t)B_ * K2_ * 4);
    float*          part  = (float*)         alloc((size_t)B_ * PB_ * 128 * 4);
    float*          x1    = (float*)         alloc((size_t)B_ * 128 * 4);
    float*          hbuf  = (float*)         alloc((size_t)B_ * 128 * 4);

    // ---- stage 1 ----
    k_zero<<<NTOT / 256, 256, 0, stream>>>(deg, NTOT);
    k_fill<false><<<ETOT / 256, 256, 0, stream>>>(src, dst, nullptr, deg, csr);
    k_rsq<false><<<NTOT / 256, 256, 0, stream>>>(deg, nullptr, rsq, nullptr, NTOT);
    k_agg<false><<<NTOT / 4, 256, 0, stream>>>(x, deg, csr, rsq, rsq, nullptr, bufA);
    k_convrow<<<NTOT / 256, 256, 0, stream>>>(bufA, W1, b1, p1, score, NTOT);
    k_select<1><<<B_, 256, 0, stream>>>(score, newid, sel1, vals1);
    k_pool<1><<<B_ * PB_, 256, 0, stream>>>(bufA, sel1, vals1, part);
    k_comb<1><<<B_, 64, 0, stream>>>(part, x1, nullptr);

    // ---- stage 2 ----
    k_zero<<<(N2TOT + 255) / 256, 256, 0, stream>>>(deg, N2TOT);
    k_fill<true><<<ETOT / 256, 256, 0, stream>>>(src, dst, newid, deg, csr);
    k_rsq<true><<<(N2TOT + 255) / 256, 256, 0, stream>>>(deg, vals1, rsq, coef, N2TOT);
    k_agg<true><<<(410 * B_), 256, 0, stream>>>(bufA, deg, csr, rsq, coef, sel1, bufB);
    k_convrow<<<(N2TOT + 255) / 256, 256, 0, stream>>>(bufB, W2, b2, p2, score, N2TOT);
    k_select<2><<<B_, 256, 0, stream>>>(score, nullptr, sel2, vals2);
    k_pool<2><<<B_ * PB_, 256, 0, stream>>>(bufB, sel2, vals2, part);
    k_comb<2><<<B_, 64, 0, stream>>>(part, x1, hbuf);

    // ---- head ----
    k_head<<<B_, 64, 0, stream>>>(hbuf, l1w, l1b, l2w, l2b, (float*)d_out);
}

// Round 6
// 495.822 us; speedup vs baseline: 2.3921x; 1.0993x over previous
//
#include <hip/hip_runtime.h>
#include <hip/hip_bf16.h>
#include <cstdint>
#include <cstddef>

#define B_    64
#define N_    2048
#define E_    32768            // edges per graph
#define DIM_  64
#define K1_   1639
#define K2_   1312
#define NTOT  (B_ * N_)        // 131072
#define ETOT  (B_ * E_)        // 2097152
#define N2TOT (B_ * K1_)       // 104896
#define NCLS  6
#define PB_   8                // pooling blocks per graph
#define CHUNKS_ 8              // dst-chunks per graph in k_build
#define CBUF  8192             // per-chunk csr capacity (avg load 4096, Poisson tail safe)

// ---------------- LDS CSR build: compact csr + nodeinfo + rsq (+coef stage2) ----------------
// One block per (graph, dst-chunk). Two passes over the graph's edges (L2-resident via
// graph->XCD affinity: b&63 = graph, XCD = graph%8). All global writes coalesced.
// nodeinfo[node] = (global_csr_start << 8) | cnt ; rsq[node] = rsqrt(cnt+1);
// STAGE2: coef[node] = vals[node] * rsq[node].
template<int STAGE>
__launch_bounds__(256)
__global__ void k_build(const int* src, const int* dst, const int* remap,
                        int* nodeinfo, unsigned short* csr, float* rsq,
                        const float* vals, float* coef) {
    const int NL = (STAGE == 1) ? N_ : K1_;
    const int LSTR = (NL + CHUNKS_ - 1) / CHUNKS_;   // 256 / 205
    __shared__ int cnt[256], inc[256], cur[256];
    __shared__ unsigned short buf[CBUF];
    int b = blockIdx.x;
    int g = b & 63, c = b >> 6;
    int tid = threadIdx.x;
    int lo = c * LSTR;
    int nloc = min(LSTR, NL - lo);
    int gbase = g * NL;
    const int* sp = src + (size_t)g * E_;
    const int* dp = dst + (size_t)g * E_;
    cnt[tid] = 0; cur[tid] = 0;
    __syncthreads();
    // pass A: count in-range dsts
    for (int e = tid * 4; e < E_; e += 1024) {
        int4 ss = *(const int4*)&sp[e];
        int4 dd = *(const int4*)&dp[e];
#pragma unroll
        for (int t = 0; t < 4; t++) {
            int s = (&ss.x)[t], d = (&dd.x)[t];
            if (STAGE == 2) { s = remap[s]; d = remap[d]; if ((s | d) < 0) continue; }
            int dl = d - gbase - lo;
            if ((unsigned)dl < (unsigned)nloc) atomicAdd(&cnt[dl], 1);
        }
    }
    __syncthreads();
    // inclusive scan of cnt -> inc
    inc[tid] = cnt[tid];
    __syncthreads();
    for (int o = 1; o < 256; o <<= 1) {
        int add = (tid >= o) ? inc[tid - o] : 0;
        __syncthreads();
        inc[tid] += add;
        __syncthreads();
    }
    // pass B: place edges at excl_start + cursor
    for (int e = tid * 4; e < E_; e += 1024) {
        int4 ss = *(const int4*)&sp[e];
        int4 dd = *(const int4*)&dp[e];
#pragma unroll
        for (int t = 0; t < 4; t++) {
            int s = (&ss.x)[t], d = (&dd.x)[t];
            if (STAGE == 2) { s = remap[s]; d = remap[d]; if ((s | d) < 0) continue; }
            int dl = d - gbase - lo;
            if ((unsigned)dl < (unsigned)nloc) {
                int p = inc[dl] - cnt[dl] + atomicAdd(&cur[dl], 1);
                if (p < CBUF) buf[p] = (unsigned short)(s - gbase);
            }
        }
    }
    __syncthreads();
    // coalesced write-out
    int total = min(inc[255], CBUF);
    int cb = b * CBUF;
    for (int i = tid; i < total; i += 256) csr[cb + i] = buf[i];
    if (tid < nloc) {
        int node = gbase + lo + tid;
        int st = cb + inc[tid] - cnt[tid];
        float rv = rsqrtf((float)(cnt[tid] + 1));
        nodeinfo[node] = (st << 8) | min(cnt[tid], 255);
        rsq[node] = rv;
        if (STAGE == 2) coef[node] = vals[node] * rv;
    }
}

// ---------------- gather-aggregate, XCD-swizzled, compact CSR ----------------
// y[d] = ( sum_{s in in(d)} xrows[row(s)]*ncoef[s] + xrows[row(d)]*selfc ) * rsq[d]
// GATE=false: row(s)=s, ncoef=rsq, selfc=rsq[d].  GATE=true: row(s)=sel[s], ncoef=coef.
template<bool GATE>
__launch_bounds__(256)
__global__ void k_agg(const float* xrows, const int* nodeinfo, const unsigned short* csr,
                      const float* ncoef, const int* sel, float* y) {
    int b = blockIdx.x;
    int xcd = b & 7, r = b >> 3;
    int graph, local;
    if (GATE) {
        graph = xcd * 8 + r / 410;            // ceil(1639/4)=410 blocks/graph
        local = (r % 410) * 4 + (threadIdx.x >> 6);
        if (local >= K1_) return;
    } else {
        graph = xcd * 8 + (r >> 9);           // 512 blocks/graph
        local = (r & 511) * 4 + (threadIdx.x >> 6);
    }
    const int NL = GATE ? K1_ : N_;
    int node = graph * NL + local;
    int lane = threadIdx.x & 63;
    int ni = nodeinfo[node];
    int cnt = ni & 255, base = ni >> 8;
    float rd = rsqrtf((float)(cnt + 1));
    float a0 = 0.f, a1 = 0.f, a2 = 0.f, a3 = 0.f;
    for (int chunk = 0; chunk < cnt; chunk += 64) {
        int nch = min(64, cnt - chunk);
        int sv = 0; float cv = 0.f;
        if (lane < nch) {
            int s = graph * NL + (int)csr[base + chunk + lane];
            sv = GATE ? sel[s] : s;
            cv = ncoef[s];
        }
        int i = 0;
        for (; i + 4 <= nch; i += 4) {
            int   r0 = __shfl(sv, i),   r1 = __shfl(sv, i+1),
                  r2 = __shfl(sv, i+2), r3 = __shfl(sv, i+3);
            float c0 = __shfl(cv, i),   c1 = __shfl(cv, i+1),
                  c2 = __shfl(cv, i+2), c3 = __shfl(cv, i+3);
            a0 += xrows[(size_t)r0 * DIM_ + lane] * c0;
            a1 += xrows[(size_t)r1 * DIM_ + lane] * c1;
            a2 += xrows[(size_t)r2 * DIM_ + lane] * c2;
            a3 += xrows[(size_t)r3 * DIM_ + lane] * c3;
        }
        for (; i < nch; i++) {
            int rr = __shfl(sv, i); float cc = __shfl(cv, i);
            a0 += xrows[(size_t)rr * DIM_ + lane] * cc;
        }
    }
    int snode = GATE ? sel[node] : node;
    float selfc = GATE ? ncoef[node] : rd;
    a0 += xrows[(size_t)snode * DIM_ + lane] * selfc;
    y[(size_t)node * DIM_ + lane] = ((a0 + a1) + (a2 + a3)) * rd;
}

// ---------------- fused conv row-matmul + bias + ReLU + score (IN PLACE on y) ---------------
__launch_bounds__(256)
__global__ void k_convrow(float* y, const float* W, const float* bias, const float* pvec,
                          float* score, int rows) {
    __shared__ float Wl[DIM_ * DIM_];
    __shared__ float bl[DIM_], pl[DIM_];
    __shared__ float rpn;
    int tid = threadIdx.x;
    for (int i = tid; i < DIM_ * DIM_; i += 256) Wl[i] = W[i];
    if (tid < DIM_) { bl[tid] = bias[tid]; pl[tid] = pvec[tid]; }
    __syncthreads();
    if (tid == 0) {
        float s = 0.0f;
        for (int i = 0; i < DIM_; i++) s += pl[i] * pl[i];
        rpn = rsqrtf(s);
    }
    __syncthreads();
    int row = blockIdx.x * 256 + tid;
    if (row >= rows) return;
    float r[DIM_];
    float4* yp = (float4*)(y + (size_t)row * DIM_);
#pragma unroll
    for (int v = 0; v < 16; v++) {
        float4 q = yp[v];
        r[4*v] = q.x; r[4*v+1] = q.y; r[4*v+2] = q.z; r[4*v+3] = q.w;
    }
    float dot = 0.0f;
#pragma unroll
    for (int jb = 0; jb < 16; jb++) {
        float4 acc = make_float4(bl[jb*4], bl[jb*4+1], bl[jb*4+2], bl[jb*4+3]);
#pragma unroll
        for (int i = 0; i < DIM_; i++) {
            float4 w4 = *(const float4*)&Wl[i * DIM_ + jb * 4];
            acc.x += r[i] * w4.x; acc.y += r[i] * w4.y;
            acc.z += r[i] * w4.z; acc.w += r[i] * w4.w;
        }
        acc.x = fmaxf(acc.x, 0.f); acc.y = fmaxf(acc.y, 0.f);
        acc.z = fmaxf(acc.z, 0.f); acc.w = fmaxf(acc.w, 0.f);
        dot += acc.x * pl[jb*4] + acc.y * pl[jb*4+1] + acc.z * pl[jb*4+2] + acc.w * pl[jb*4+3];
        yp[jb] = acc;
    }
    score[row] = tanhf(dot * rpn);
}

// ---------------- exact top-K: 6-pass radix select, parallel suffix-sum bin scan ------------
template<int STAGE>
__launch_bounds__(256)
__global__ void k_select(const float* score, int* new_id, int* sel, float* vals) {
    const int Nin = (STAGE == 1) ? N_ : K1_;
    const int K   = (STAGE == 1) ? K1_ : K2_;
    __shared__ unsigned long long keys[N_];
    __shared__ int bins[256], ts[256];
    __shared__ unsigned long long s_prefix;
    __shared__ int s_need, s_cnt;
    int g = blockIdx.x, tid = threadIdx.x;
    const float* sg = score + (size_t)g * Nin;
    for (int i = tid; i < Nin; i += 256) {
        unsigned u = __float_as_uint(sg[i]);
        u = (u & 0x80000000u) ? ~u : (u | 0x80000000u);
        keys[i] = ((unsigned long long)u << 11) | (unsigned long long)(2047 - i);
    }
    if (tid == 0) { s_need = K; s_prefix = 0ull; s_cnt = 0; }
    __syncthreads();
    for (int shift = 40; shift >= 0; shift -= 8) {
        bins[tid] = 0;
        __syncthreads();
        unsigned long long pref = s_prefix;
        int need = s_need;
        int hi = shift + 8;
        for (int i = tid; i < Nin; i += 256) {
            unsigned long long k = keys[i];
            if ((k >> hi) == pref) atomicAdd(&bins[(int)((k >> shift) & 255)], 1);
        }
        __syncthreads();
        ts[tid] = bins[tid];
        __syncthreads();
        for (int o = 1; o < 256; o <<= 1) {      // suffix sum
            int add = (tid + o < 256) ? ts[tid + o] : 0;
            __syncthreads();
            ts[tid] += add;
            __syncthreads();
        }
        int nxt = (tid == 255) ? 0 : ts[tid + 1];
        if (ts[tid] >= need && nxt < need) {     // exactly one tid matches
            s_prefix = (pref << 8) | (unsigned long long)tid;
            s_need = need - nxt;
        }
        __syncthreads();
    }
    unsigned long long T = s_prefix;
    for (int i = tid; i < Nin; i += 256) {
        if (keys[i] >= T) {
            int r = atomicAdd(&s_cnt, 1);
            int slot = g * K + r;
            sel[slot]  = g * Nin + i;
            vals[slot] = sg[i];
            if (STAGE == 1) new_id[g * N_ + i] = slot;
        } else if (STAGE == 1) {
            new_id[g * N_ + i] = -1;
        }
    }
}

// ---------------- gated max/mean pooling, PB_ blocks per graph (XCD-swizzled) ---------------
template<int STAGE>
__launch_bounds__(256)
__global__ void k_pool(const float* conv, const int* sel, const float* vals, float* part) {
    const int K = (STAGE == 1) ? K1_ : K2_;
    int b = blockIdx.x;
    int xcd = b & 7, t = b >> 3;
    int g = xcd * 8 + (t >> 3), c = t & 7;
    int wv = threadIdx.x >> 6, lane = threadIdx.x & 63;
    float mx = -3.402823466e38f, sm = 0.f;
    for (int r = c * 4 + wv; r < K; r += PB_ * 4) {
        int slot = g * K + r;
        int row  = sel[slot];
        float val = vals[slot];
        float v = conv[(size_t)row * DIM_ + lane] * val;
        mx = fmaxf(mx, v);
        sm += v;
    }
    __shared__ float rmx[4][64], rsm[4][64];
    rmx[wv][lane] = mx; rsm[wv][lane] = sm;
    __syncthreads();
    if (wv == 0) {
        mx = fmaxf(fmaxf(rmx[0][lane], rmx[1][lane]), fmaxf(rmx[2][lane], rmx[3][lane]));
        sm = rsm[0][lane] + rsm[1][lane] + rsm[2][lane] + rsm[3][lane];
        part[((size_t)(g * PB_ + c) * 2 + 0) * 64 + lane] = mx;
        part[((size_t)(g * PB_ + c) * 2 + 1) * 64 + lane] = sm;
    }
}

// ---------------- combine partials -> x1 (stage1) or hbuf = x1 + x2 (stage2) ----------------
template<int STAGE>
__launch_bounds__(64)
__global__ void k_comb(const float* part, float* x1, float* hbuf) {
    const int K = (STAGE == 1) ? K1_ : K2_;
    int g = blockIdx.x, lane = threadIdx.x;
    float mx = -3.402823466e38f, sm = 0.f;
    for (int c = 0; c < PB_; c++) {
        mx = fmaxf(mx, part[((size_t)(g * PB_ + c) * 2 + 0) * 64 + lane]);
        sm += part[((size_t)(g * PB_ + c) * 2 + 1) * 64 + lane];
    }
    float mean = sm / (float)K;
    if (STAGE == 1) {
        x1[g * 128 + lane]      = mx;
        x1[g * 128 + 64 + lane] = mean;
    } else {
        hbuf[g * 128 + lane]      = x1[g * 128 + lane] + mx;
        hbuf[g * 128 + 64 + lane] = x1[g * 128 + 64 + lane] + mean;
    }
}

// ---------------- MLP head ----------------
__launch_bounds__(64)
__global__ void k_head(const float* hbuf, const float* l1w, const float* l1b,
                       const float* l2w, const float* l2b, float* out) {
    __shared__ float h[128];
    __shared__ float h1[64];
    int g = blockIdx.x, t = threadIdx.x;
    h[t]      = hbuf[g * 128 + t];
    h[t + 64] = hbuf[g * 128 + 64 + t];
    __syncthreads();
    float acc = l1b[t];
#pragma unroll 8
    for (int i = 0; i < 128; i++) acc += h[i] * l1w[i * 64 + t];
    h1[t] = fmaxf(acc, 0.0f);
    __syncthreads();
    if (t < NCLS) {
        float o = l2b[t];
#pragma unroll
        for (int i = 0; i < 64; i++) o += h1[i] * l2w[i * NCLS + t];
        out[g * NCLS + t] = o;
    }
}

extern "C" void kernel_launch(void* const* d_in, const int* in_sizes, int n_in,
                              void* d_out, int out_size, void* d_ws, size_t ws_size,
                              hipStream_t stream) {
    const float* x   = (const float*)d_in[0];
    const int*   ei  = (const int*)d_in[1];
    const int*   src = ei;
    const int*   dst = ei + ETOT;
    const float* W1  = (const float*)d_in[3];
    const float* b1  = (const float*)d_in[4];
    const float* p1  = (const float*)d_in[5];
    const float* W2  = (const float*)d_in[6];
    const float* b2  = (const float*)d_in[7];
    const float* p2  = (const float*)d_in[8];
    const float* l1w = (const float*)d_in[9];
    const float* l1b = (const float*)d_in[10];
    const float* l2w = (const float*)d_in[11];
    const float* l2b = (const float*)d_in[12];
    (void)in_sizes; (void)n_in; (void)out_size; (void)ws_size;

    // workspace layout (~72 MB)
    char* ws = (char*)d_ws;
    size_t off = 0;
    auto alloc = [&](size_t bytes) -> void* {
        void* p = ws + off;
        off = (off + bytes + 255) & ~(size_t)255;
        return p;
    };
    float*          bufA  = (float*)         alloc((size_t)NTOT  * DIM_ * 4); // y1 -> conv1
    float*          bufB  = (float*)         alloc((size_t)N2TOT * DIM_ * 4); // y2 -> conv2
    unsigned short* csr   = (unsigned short*)alloc((size_t)B_ * CHUNKS_ * CBUF * 2); // 8 MB
    int*            ninfo = (int*)           alloc((size_t)NTOT * 4);
    float*          rsq   = (float*)         alloc((size_t)NTOT * 4);
    float*          coef  = (float*)         alloc((size_t)N2TOT * 4);
    float*          score = (float*)         alloc((size_t)NTOT * 4);
    int*            newid = (int*)           alloc((size_t)NTOT * 4);
    int*            sel1  = (int*)           alloc((size_t)N2TOT * 4);
    float*          vals1 = (float*)         alloc((size_t)N2TOT * 4);
    int*            sel2  = (int*)           alloc((size_t)B_ * K2_ * 4);
    float*          vals2 = (float*)         alloc((size_t)B_ * K2_ * 4);
    float*          part  = (float*)         alloc((size_t)B_ * PB_ * 128 * 4);
    float*          x1    = (float*)         alloc((size_t)B_ * 128 * 4);
    float*          hbuf  = (float*)         alloc((size_t)B_ * 128 * 4);

    // ---- stage 1 ----
    k_build<1><<<B_ * CHUNKS_, 256, 0, stream>>>(src, dst, nullptr, ninfo, csr, rsq, nullptr, nullptr);
    k_agg<false><<<NTOT / 4, 256, 0, stream>>>(x, ninfo, csr, rsq, nullptr, bufA);
    k_convrow<<<NTOT / 256, 256, 0, stream>>>(bufA, W1, b1, p1, score, NTOT);
    k_select<1><<<B_, 256, 0, stream>>>(score, newid, sel1, vals1);
    k_pool<1><<<B_ * PB_, 256, 0, stream>>>(bufA, sel1, vals1, part);
    k_comb<1><<<B_, 64, 0, stream>>>(part, x1, nullptr);

    // ---- stage 2 ----
    k_build<2><<<B_ * CHUNKS_, 256, 0, stream>>>(src, dst, newid, ninfo, csr, rsq, vals1, coef);
    k_agg<true><<<410 * B_, 256, 0, stream>>>(bufA, ninfo, csr, coef, sel1, bufB);
    k_convrow<<<(N2TOT + 255) / 256, 256, 0, stream>>>(bufB, W2, b2, p2, score, N2TOT);
    k_select<2><<<B_, 256, 0, stream>>>(score, nullptr, sel2, vals2);
    k_pool<2><<<B_ * PB_, 256, 0, stream>>>(bufB, sel2, vals2, part);
    k_comb<2><<<B_, 64, 0, stream>>>(part, x1, hbuf);

    // ---- head ----
    k_head<<<B_, 64, 0, stream>>>(hbuf, l1w, l1b, l2w, l2b, (float*)d_out);
}